// Round 1
// baseline (916.445 us; speedup 1.0000x reference)
//
#include <hip/hip_runtime.h>
#include <hip/hip_bf16.h>

using u16 = unsigned short;
typedef __bf16 bf16x8 __attribute__((ext_vector_type(8)));
typedef float f32x4 __attribute__((ext_vector_type(4)));
typedef u16 u16x8 __attribute__((ext_vector_type(8)));
typedef u16 u16x4 __attribute__((ext_vector_type(4)));

constexpr int T_SEQ = 2048;
constexpr int HID   = 4096;
constexpr int NH    = 32;
constexpr int NKV   = 8;
constexpr int HD    = 128;
constexpr int QKVN  = 6144;   // 32*128 + 2*8*128

__device__ __forceinline__ u16 f2b(float x) {
  return __builtin_bit_cast(u16, __float2bfloat16(x));
}
__device__ __forceinline__ float b2f(u16 u) {
  return __builtin_bit_cast(float, (unsigned int)u << 16);
}
__device__ __forceinline__ bf16x8 load8(const u16* p) {
  return __builtin_bit_cast(bf16x8, *reinterpret_cast<const u16x8*>(p));
}
__device__ __forceinline__ f32x4 mfma16(bf16x8 a, bf16x8 b, f32x4 c) {
  return __builtin_amdgcn_mfma_f32_16x16x32_bf16(a, b, c, 0, 0, 0);
}

// ---------------- cast fp32 -> bf16 (vectorized) ----------------
__global__ __launch_bounds__(256) void k_cast_bf16(const float* __restrict__ in,
                                                   u16* __restrict__ out, int n4) {
  int i = blockIdx.x * 256 + threadIdx.x;
  if (i < n4) {
    float4 v = reinterpret_cast<const float4*>(in)[i];
    u16x4 o;
    o.x = f2b(v.x); o.y = f2b(v.y); o.z = f2b(v.z); o.w = f2b(v.w);
    reinterpret_cast<u16x4*>(out)[i] = o;
  }
}

// ---------------- transpose + cast: in[R][C] fp32 -> out[C][R] bf16 ----------------
__global__ __launch_bounds__(256) void k_transpose_cast(const float* __restrict__ in,
                                                        u16* __restrict__ out,
                                                        int R, int C) {
  __shared__ float tile[32][33];
  int cc = blockIdx.x << 5, rr = blockIdx.y << 5;
  int lx = threadIdx.x & 31, ly = threadIdx.x >> 5;
#pragma unroll
  for (int i = 0; i < 32; i += 8)
    tile[ly + i][lx] = in[(size_t)(rr + ly + i) * C + cc + lx];
  __syncthreads();
#pragma unroll
  for (int i = 0; i < 32; i += 8)
    out[(size_t)(cc + ly + i) * R + rr + lx] = f2b(tile[lx][ly + i]);
}

// ---------------- bf16 GEMM: C[M][N] = A[M][K] * B[N][K]^T ----------------
// 128x128 tile, BK=32, 4 waves (2x2 of 64x64), global_load_lds w16,
// XOR k-slot swizzle: LDS[row][slot] holds k-slot (slot ^ ((row>>1)&3)).
template <int N, int K, typename OutT>
__global__ __launch_bounds__(256) void k_gemm_bt(const u16* __restrict__ A,
                                                 const u16* __restrict__ B,
                                                 OutT* __restrict__ C) {
  __shared__ u16 lA[128 * 32];
  __shared__ u16 lB[128 * 32];
  const int tid = threadIdx.x;
  const int wid = tid >> 6, lane = tid & 63;
  const int row0 = blockIdx.y << 7, col0 = blockIdx.x << 7;
  const int wr = wid >> 1, wc = wid & 1;
  const int g = lane >> 4, c = lane & 15;

  f32x4 acc[4][4] = {};

  const int r_st = lane >> 2;      // row within 16-row wave chunk
  const int slot_st = lane & 3;    // 16B slot within 64B row

  const int rA0 = wr * 64 + c;
  const int rB0 = wc * 64 + c;
  const int swzA = (rA0 >> 1) & 3;  // invariant under +16 row steps
  const int swzB = (rB0 >> 1) & 3;

  for (int kt = 0; kt < K / 32; ++kt) {
    const int kk = kt * 32;
#pragma unroll
    for (int i = 0; i < 2; ++i) {
      int r = wid * 16 + i * 64 + r_st;
      int s = slot_st ^ ((r >> 1) & 3);
      const u16* ga = A + (size_t)(row0 + r) * K + kk + s * 8;
      const u16* gb = B + (size_t)(col0 + r) * K + kk + s * 8;
      char* la = (char*)lA + wid * 1024 + i * 4096;  // wave-uniform base
      char* lb = (char*)lB + wid * 1024 + i * 4096;
      __builtin_amdgcn_global_load_lds((const __attribute__((address_space(1))) void*)ga,
                                       (__attribute__((address_space(3))) void*)la, 16, 0, 0);
      __builtin_amdgcn_global_load_lds((const __attribute__((address_space(1))) void*)gb,
                                       (__attribute__((address_space(3))) void*)lb, 16, 0, 0);
    }
    __syncthreads();

    bf16x8 af[4], bfr[4];
#pragma unroll
    for (int m = 0; m < 4; ++m) {
      int row = rA0 + m * 16;
      af[m] = load8(lA + row * 32 + (g ^ swzA) * 8);
    }
#pragma unroll
    for (int n = 0; n < 4; ++n) {
      int row = rB0 + n * 16;
      bfr[n] = load8(lB + row * 32 + (g ^ swzB) * 8);
    }
#pragma unroll
    for (int m = 0; m < 4; ++m)
#pragma unroll
      for (int n = 0; n < 4; ++n)
        acc[m][n] = mfma16(af[m], bfr[n], acc[m][n]);
    __syncthreads();
  }

  // epilogue: D layout col=lane&15, row=(lane>>4)*4+reg  (m89-verified)
#pragma unroll
  for (int m = 0; m < 4; ++m) {
    int grow0 = row0 + wr * 64 + m * 16 + g * 4;
#pragma unroll
    for (int n = 0; n < 4; ++n) {
      int gcol = col0 + wc * 64 + n * 16 + c;
#pragma unroll
      for (int j = 0; j < 4; ++j) {
        float v = acc[m][n][j];
        if constexpr (sizeof(OutT) == 2)
          C[(size_t)(grow0 + j) * N + gcol] = f2b(v);
        else
          C[(size_t)(grow0 + j) * N + gcol] = v;
      }
    }
  }
}

// ---------------- fused per-head RMSNorm + RoPE + scale, qkv split ----------------
// qkv: [T][QKVN] bf16. One wave per (t, head). h<32: q, 32..39: k, 40..47: v.
__global__ __launch_bounds__(256) void k_normrope(const u16* __restrict__ qkv,
                                                  const int* __restrict__ pos,
                                                  const float* __restrict__ qw,
                                                  const float* __restrict__ kw,
                                                  u16* __restrict__ qo,
                                                  u16* __restrict__ ko,
                                                  u16* __restrict__ vo) {
  int t = blockIdx.x;
  int wid = threadIdx.x >> 6, lane = threadIdx.x & 63;
  int h = blockIdx.y * 4 + wid;  // 0..47
  const u16* src = qkv + (size_t)t * QKVN + h * HD;
  float x1 = b2f(src[lane]), x2 = b2f(src[lane + 64]);
  float ss = x1 * x1 + x2 * x2;
#pragma unroll
  for (int m = 1; m < 64; m <<= 1) ss += __shfl_xor(ss, m);
  float sc = rsqrtf(ss * (1.0f / HD) + 1e-6f);
  if (h < 40) {
    const float* w = (h < NH) ? qw : kw;
    float y1 = x1 * sc * w[lane], y2 = x2 * sc * w[lane + 64];
    float p = (float)pos[t];
    float inv = powf(10000.0f, -(float)lane * (1.0f / 64.0f));
    float ang = p * inv;
    float sn, cs;
    sincosf(ang, &sn, &cs);
    float o1 = y1 * cs - y2 * sn;
    float o2 = y2 * cs + y1 * sn;
    if (h < NH) {
      o1 *= 0.08838834764831845f;  // fold 1/sqrt(128) into q
      o2 *= 0.08838834764831845f;
      u16* dst = qo + ((size_t)t * NH + h) * HD;
      dst[lane] = f2b(o1);
      dst[lane + 64] = f2b(o2);
    } else {
      u16* dst = ko + ((size_t)t * NKV + (h - NH)) * HD;
      dst[lane] = f2b(o1);
      dst[lane + 64] = f2b(o2);
    }
  } else {
    u16* dst = vo + ((size_t)t * NKV + (h - 40)) * HD;
    dst[lane] = f2b(x1);
    dst[lane + 64] = f2b(x2);
  }
}

// ---------------- V transpose: vb[T][NKV][HD] -> vt[NKV][HD][T] ----------------
__global__ __launch_bounds__(256) void k_transpose_v(const u16* __restrict__ vb,
                                                     u16* __restrict__ vt) {
  __shared__ u16 tile[32][33];
  int tt = blockIdx.x << 5, dd = blockIdx.y << 5, h = blockIdx.z;
  int lx = threadIdx.x & 31, ly = threadIdx.x >> 5;
#pragma unroll
  for (int i = 0; i < 32; i += 8)
    tile[ly + i][lx] = vb[((size_t)(tt + ly + i) * NKV + h) * HD + dd + lx];
  __syncthreads();
#pragma unroll
  for (int i = 0; i < 32; i += 8)
    vt[((size_t)h * HD + dd + ly + i) * T_SEQ + tt + lx] = tile[lx][ly + i];
}

// ---------------- flash attention: 1 wave per (head, 16-row q tile) ----------------
__global__ __launch_bounds__(64) void k_attn(const u16* __restrict__ qb,
                                             const u16* __restrict__ kbp,
                                             const u16* __restrict__ vt,
                                             u16* __restrict__ out) {
  __shared__ u16 p_sh[16 * 32];
  const int qt = blockIdx.x, h = blockIdx.y;
  const int hk = h >> 2;
  const int lane = threadIdx.x;
  const int g = lane >> 4, c = lane & 15;
  const int qb0 = qt * 16;

  // Q fragments: A[row=c][k = kc*32 + g*8 + j]
  bf16x8 qf[4];
  const u16* qrow = qb + ((size_t)(qb0 + c) * NH + h) * HD;
#pragma unroll
  for (int kc = 0; kc < 4; ++kc) qf[kc] = load8(qrow + kc * 32 + g * 8);

  f32x4 accO[8] = {};                     // col = c2*16 + c, row = g*4 + j
  float m_[4] = {-1e30f, -1e30f, -1e30f, -1e30f};
  float l_[4] = {0.f, 0.f, 0.f, 0.f};

  const u16* vtb = vt + (size_t)hk * HD * T_SEQ;
  const int ntiles = (qb0 + 47) >> 5;

  for (int kt = 0; kt < ntiles; ++kt) {
    const int kvb = kt * 32;
    f32x4 s0 = {0.f, 0.f, 0.f, 0.f}, s1 = {0.f, 0.f, 0.f, 0.f};
    const u16* k0 = kbp + ((size_t)(kvb + c) * NKV + hk) * HD;
    const u16* k1 = kbp + ((size_t)(kvb + 16 + c) * NKV + hk) * HD;
#pragma unroll
    for (int kc = 0; kc < 4; ++kc) {
      s0 = mfma16(qf[kc], load8(k0 + kc * 32 + g * 8), s0);
      s1 = mfma16(qf[kc], load8(k1 + kc * 32 + g * 8), s1);
    }

    const int tq0 = qb0 + g * 4;
    const int tk0 = kvb + c, tk1 = kvb + 16 + c;
    float al[4];
#pragma unroll
    for (int j = 0; j < 4; ++j) {
      int tq = tq0 + j;
      float v0 = (tk0 <= tq) ? s0[j] : -1e30f;
      float v1 = (tk1 <= tq) ? s1[j] : -1e30f;
      float mx = fmaxf(v0, v1);
#pragma unroll
      for (int msk = 1; msk < 16; msk <<= 1) mx = fmaxf(mx, __shfl_xor(mx, msk));
      float mn = fmaxf(m_[j], mx);
      float a = __expf(m_[j] - mn);
      float p0 = __expf(v0 - mn);
      float p1 = __expf(v1 - mn);
      float ps = p0 + p1;
#pragma unroll
      for (int msk = 1; msk < 16; msk <<= 1) ps += __shfl_xor(ps, msk);
      l_[j] = l_[j] * a + ps;
      m_[j] = mn;
      al[j] = a;
      p_sh[(g * 4 + j) * 32 + c] = f2b(p0);
      p_sh[(g * 4 + j) * 32 + 16 + c] = f2b(p1);
    }
    // rescale running O
#pragma unroll
    for (int c2 = 0; c2 < 8; ++c2)
#pragma unroll
      for (int j = 0; j < 4; ++j) accO[c2][j] *= al[j];

    // P fragment (transposed via LDS): A[row=c][k=g*8+j]
    bf16x8 pf = load8(p_sh + c * 32 + g * 8);
#pragma unroll
    for (int c2 = 0; c2 < 8; ++c2) {
      bf16x8 vf = load8(vtb + (size_t)(c2 * 16 + c) * T_SEQ + kvb + g * 8);
      accO[c2] = mfma16(pf, vf, accO[c2]);
    }
  }

#pragma unroll
  for (int c2 = 0; c2 < 8; ++c2)
#pragma unroll
    for (int j = 0; j < 4; ++j) {
      float o = accO[c2][j] / l_[j];
      out[(size_t)(qb0 + g * 4 + j) * HID + h * HD + c2 * 16 + c] = f2b(o);
    }
}

// ---------------- launch ----------------
extern "C" void kernel_launch(void* const* d_in, const int* in_sizes, int n_in,
                              void* d_out, int out_size, void* d_ws, size_t ws_size,
                              hipStream_t stream) {
  (void)in_sizes; (void)n_in; (void)out_size; (void)ws_size;
  const float* x      = (const float*)d_in[0];
  const int*   pos    = (const int*)d_in[1];
  const float* qkv_w  = (const float*)d_in[2];
  const float* qnw    = (const float*)d_in[3];
  const float* knw    = (const float*)d_in[4];
  const float* ow     = (const float*)d_in[5];
  float* out = (float*)d_out;
  char* ws = (char*)d_ws;

  // region A (16,777,216 B): xb then attn
  u16* xb   = (u16*)(ws + 0);
  u16* attn = (u16*)(ws + 0);
  // region B (50,331,648 B): qkv_wt then {qb, kb, vb, vt}
  char* B0 = ws + 16777216;
  u16* qkv_wt = (u16*)B0;
  u16* qbuf = (u16*)(B0 + 0);
  u16* kbuf = (u16*)(B0 + 16777216);
  u16* vbuf = (u16*)(B0 + 20971520);
  u16* vtb  = (u16*)(B0 + 25165824);
  // region C (33,554,432 B): qkv bf16 then o_wt
  char* C0 = ws + 67108864;
  u16* qkvb = (u16*)C0;
  u16* o_wt = (u16*)C0;

  // 1. cast x -> bf16
  k_cast_bf16<<<dim3((T_SEQ * HID / 4 + 255) / 256), 256, 0, stream>>>(x, xb, T_SEQ * HID / 4);
  // 2. transpose-cast qkv_w [4096][6144] -> [6144][4096] bf16
  k_transpose_cast<<<dim3(QKVN / 32, HID / 32), 256, 0, stream>>>(qkv_w, qkv_wt, HID, QKVN);
  // 3. qkv GEMM -> bf16 [T][6144]
  k_gemm_bt<QKVN, HID, u16><<<dim3(QKVN / 128, T_SEQ / 128), 256, 0, stream>>>(xb, qkv_wt, qkvb);
  // 4. rmsnorm + rope + split (overwrites region B; qkv_wt dead)
  k_normrope<<<dim3(T_SEQ, 12), 256, 0, stream>>>(qkvb, pos, qnw, knw, qbuf, kbuf, vbuf);
  // 5. V transpose [T][8][128] -> [8][128][T]
  k_transpose_v<<<dim3(T_SEQ / 32, HD / 32, NKV), 256, 0, stream>>>(vbuf, vtb);
  // 6. transpose-cast o_w -> [N][K] bf16 (overwrites region C; qkvb dead)
  k_transpose_cast<<<dim3(HID / 32, HID / 32), 256, 0, stream>>>(ow, o_wt, HID, HID);
  // 7. attention -> attn bf16 [T][4096] (overwrites region A; xb dead)
  k_attn<<<dim3(T_SEQ / 16, NH), 64, 0, stream>>>(qbuf, kbuf, vtb, attn);
  // 8. output GEMM -> fp32 d_out
  k_gemm_bt<HID, HID, float><<<dim3(HID / 128, T_SEQ / 128), 256, 0, stream>>>(attn, o_wt, out);
}